// Round 14
// baseline (147.593 us; speedup 1.0000x reference)
//
#include <hip/hip_runtime.h>
#include <math.h>

#define NQ 12
#define DIM 4096
#define NLAYER 4
#define NT 512

typedef float v2 __attribute__((ext_vector_type(2)));

__device__ __forceinline__ v2 mkv2(float a, float b) { v2 r; r.x = a; r.y = b; return r; }
__device__ __forceinline__ v2 sp(float a) { v2 r; r.x = a; r.y = a; return r; }
__device__ __forceinline__ v2 pkfma(v2 a, float b, v2 c) {
  return __builtin_elementwise_fma(a, sp(b), c);
}

// Compiler reorder fence (zero instructions): keeps LDS ops of consecutive
// wave-private passes in program order; HW executes a wave's DS ops in order.
#define CFENCE asm volatile("" ::: "memory")

// CNOT-cascade gather map (verified R1-R13): post-perm label y sits at sfun(y).
constexpr int sfun_c(int z) { z ^= z >> 1; z ^= z >> 2; z ^= z >> 4; z ^= z >> 8; return z & (DIM - 1); }
__device__ __forceinline__ int sfun_d(int z) { z ^= z >> 1; z ^= z >> 2; z ^= z >> 4; z ^= z >> 8; return z & (DIM - 1); }
// New swizzle: low6 ^= z{6-8} ^ z{9-11} ^ (z{9-11}<<3). Unit-triangular ->
// bijective. Rank-6 lane-bijectivity verified for ALL patterns used below
// (alpha, beta, gamma, delta, encode, gather-alpha, out-gather).
constexpr int swz_c(int z) {
  return z ^ ((z >> 6) & 7) ^ ((z >> 9) & 7) ^ (((z >> 9) & 7) << 3);
}
__device__ __forceinline__ int swz_d(int z) {
  return z ^ ((z >> 6) & 7) ^ ((z >> 9) & 7) ^ (((z >> 9) & 7) << 3);
}

// Compile-time XOR byte-offset tables (swz, sfun GF(2)-linear).
struct KT { int A[8], B[8], C[8], D[8], G[8]; };
constexpr KT mkKT() {
  KT k{};
  for (int j = 0; j < 8; ++j) {
    k.A[j] = swz_c(j << 9) << 4;           // alpha: j = z{9-11}
    k.B[j] = swz_c(j << 6) << 4;           // beta:  j = z{6-8}
    k.C[j] = swz_c(j << 3) << 4;           // gamma: j = z{3-5}
    k.D[j] = swz_c(j) << 4;                // delta: j = z{0-2} (also encode)
    k.G[j] = swz_c(sfun_c(j << 9)) << 4;   // CNOT gather composed with alpha
  }
  return k;
}
constexpr KT KTab = mkKT();

__device__ __forceinline__ v2 block_reduce_sum2(v2 v, v2* red) {
  const int tid = threadIdx.x;
#pragma unroll
  for (int off = 32; off > 0; off >>= 1) {
    v.x += __shfl_down(v.x, off, 64);
    v.y += __shfl_down(v.y, off, 64);
  }
  if ((tid & 63) == 0) red[tid >> 6] = v;
  __syncthreads();
  if (tid == 0) {
    v2 s = sp(0.f);
#pragma unroll
    for (int i = 0; i < NT / 64; ++i) s += red[i];
    red[0] = s;
  }
  __syncthreads();
  v2 r = red[0];
  __syncthreads();
  return r;
}

// Packed complex pair update, two rows at once (v_pk_fma_f32 material).
__device__ __forceinline__ void apply_pair(v2& r0, v2& i0, v2& r1, v2& i1,
    const float2 u00, const float2 u01, const float2 u10, const float2 u11) {
  v2 nr0 = pkfma(i1, -u01.y, pkfma(r1, u01.x, pkfma(i0, -u00.y, r0 * sp(u00.x))));
  v2 ni0 = pkfma(r1,  u01.y, pkfma(i1, u01.x, pkfma(r0,  u00.y, i0 * sp(u00.x))));
  v2 nr1 = pkfma(i1, -u11.y, pkfma(r1, u11.x, pkfma(i0, -u10.y, r0 * sp(u10.x))));
  v2 ni1 = pkfma(r1,  u11.y, pkfma(i1, u11.x, pkfma(r0,  u10.y, i0 * sp(u10.x))));
  r0 = nr0; i0 = ni0; r1 = nr1; i1 = ni1;
}

// Pass RT: reg slot-bit i holds z-bit (9-3*RT)+i -> qubit (2+3*RT)-i.
// alpha=RT0, beta=RT1, gamma=RT2, delta=RT3 (same templates as R7, verified).
template <int RT>
__device__ __forceinline__ void gates3(v2 re[8], v2 im[8], const float2* GL) {
#pragma unroll
  for (int i = 0; i < 3; ++i) {
    const int q = 2 + 3 * RT - i;
    const float2 u00 = GL[q * 4 + 0], u01 = GL[q * 4 + 1];
    const float2 u10 = GL[q * 4 + 2], u11 = GL[q * 4 + 3];
#pragma unroll
    for (int pe = 0; pe < 4; ++pe) {
      const int e0 = ((pe >> i) << (i + 1)) | (pe & ((1 << i) - 1));
      const int e1 = e0 | (1 << i);
      apply_pair(re[e0], im[e0], re[e1], im[e1], u00, u01, u10, u11);
    }
  }
}

#define LOAD8(BB, KARR)                                                \
  _Pragma("unroll")                                                    \
  for (int j = 0; j < 8; ++j) {                                        \
    const float4 v = *(const float4*)(st + ((BB) ^ KTab.KARR[j]));     \
    re[j] = mkv2(v.x, v.y);                                            \
    im[j] = mkv2(v.z, v.w);                                            \
  }
#define STORE8(BB, KARR)                                               \
  _Pragma("unroll")                                                    \
  for (int j = 0; j < 8; ++j)                                          \
    *(float4*)(st + ((BB) ^ KTab.KARR[j])) =                           \
        make_float4(re[j].x, re[j].y, im[j].x, im[j].y);

__global__ __launch_bounds__(NT, 4) void qsim_kernel(
    const float* __restrict__ x, const float* __restrict__ w,
    float* __restrict__ out) {
  extern __shared__ __align__(16) char smem[];
  char*   st   = smem;                           // 64 KB: unit=(re0,re1,im0,im1)
  float2* gmat = (float2*)(smem + DIM * 16);     // 1.5 KB
  v2*     red  = (v2*)(gmat + NLAYER * NQ * 4);  // 64 B

  const int t = threadIdx.x;
  const int lane = t & 63, wave = t >> 6;
  const long r0 = 2L * blockIdx.x;

  // --- gate matrices (48 gates, one thread each) ---
  if (t < NLAYER * NQ) {
    const float* wp = w + t * 3;
    float phi = wp[0], th = wp[1], om = wp[2];
    float sn, cc, sa, ca, sb, cb;
    sincosf(0.5f * th, &sn, &cc);
    sincosf(0.5f * (phi + om), &sa, &ca);
    sincosf(0.5f * (phi - om), &sb, &cb);
    float2* g = &gmat[t * 4];
    g[0] = make_float2(ca * cc, -sa * cc);   // U00
    g[1] = make_float2(-cb * sn, -sb * sn);  // U01
    g[2] = make_float2(cb * sn, -sb * sn);   // U10
    g[3] = make_float2(ca * cc, sa * cc);    // U11
  }

  // --- load 8 consecutive x from each of 2 rows, norms ---
  const float4* xa = (const float4*)(x + r0 * DIM) + t * 2;
  const float4* xb = (const float4*)(x + (r0 + 1) * DIM) + t * 2;
  const float4 a0 = xa[0], a1 = xa[1], b0 = xb[0], b1 = xb[1];
  const float va[8] = {a0.x, a0.y, a0.z, a0.w, a1.x, a1.y, a1.z, a1.w};
  const float vb[8] = {b0.x, b0.y, b0.z, b0.w, b1.x, b1.y, b1.z, b1.w};
  v2 ss = sp(0.f);
#pragma unroll
  for (int e = 0; e < 8; ++e) { ss.x += va[e] * va[e]; ss.y += vb[e] * vb[e]; }
  const v2 nsq = block_reduce_sum2(ss, red);   // barriers also cover gmat init
  const float n0 = sqrtf(nsq.x), n1 = sqrtf(nsq.y);
  const bool ok0 = n0 > 1e-10f, ok1 = n1 > 1e-10f;
  const float i0f = ok0 ? 1.0f / n0 : 0.f, i1f = ok1 ? 1.0f / n1 : 0.f;

  // --- pattern bases (unit index -> byte) ---
  // alpha: z = wave | lane<<3 | j<<9   (ownership: z{0-2} = wave)
  // beta:  z = wave | (lane&7)<<3 | j<<6 | (lane>>3)<<9
  // gamma: z = wave | j<<3 | lane<<6
  // delta: z = j | lane<<3 | wave<<9   (cross-wave; also encode)
  const int baseAb = swz_d(wave | (lane << 3)) << 4;
  const int baseBb = swz_d(wave | ((lane & 7) << 3) | ((lane >> 3) << 9)) << 4;
  const int baseCb = swz_d(wave | (lane << 6)) << 4;
  const int baseDb = swz_d((lane << 3) | (wave << 9)) << 4;
  const int baseGb = swz_d(sfun_d(wave | (lane << 3))) << 4;
  const int baseOb = swz_d(sfun_d(t)) << 4;

  // encode (delta pattern): logical z = t*8 + e -> j=e, lane=z{3-8}, wave=z{9-11}
#pragma unroll
  for (int e = 0; e < 8; ++e)
    *(float4*)(st + (baseDb ^ KTab.D[e])) =
        make_float4(ok0 ? va[e] * i0f : 0.015625f,
                    ok1 ? vb[e] * i1f : 0.015625f, 0.f, 0.f);
  __syncthreads();

  v2 re[8], im[8];
#pragma unroll
  for (int L = 0; L < NLAYER; ++L) {
    const float2* GL = &gmat[L * NQ * 4];

    // alpha: z-bits 9-11 (qubits 2,1,0). L>=1 fuses prev layer's CNOT perm.
    if (L == 0) {
      LOAD8(baseAb, A)
      gates3<0>(re, im, GL);
      STORE8(baseAb, A)          // thread-local in-place, no barrier
    } else {
      LOAD8(baseGb, G)
      gates3<0>(re, im, GL);
      __syncthreads();           // all gather reads done before in-place writes
      STORE8(baseAb, A)
    }
    CFENCE;
    // beta: z-bits 6-8 (qubits 5,4,3) — wave-private, NO barrier
    LOAD8(baseBb, B)
    gates3<1>(re, im, GL);
    STORE8(baseBb, B)
    CFENCE;
    // gamma: z-bits 3-5 (qubits 8,7,6) — wave-private, NO barrier
    LOAD8(baseCb, C)
    gates3<2>(re, im, GL);
    STORE8(baseCb, C)
    __syncthreads();             // delta crosses waves
    // delta: z-bits 0-2 (qubits 11,10,9) — thread-local in-place
    LOAD8(baseDb, D)
    gates3<3>(re, im, GL);
    STORE8(baseDb, D)
    __syncthreads();             // next alpha-gather / output reads everything
  }

  // --- output: final perm fused into gather; probs + renormalize, 2 rows ---
  float q0[8], q1[8];
  v2 ps = sp(0.f);
#pragma unroll
  for (int k = 0; k < 8; ++k) {
    const float4 v = *(const float4*)(st + (baseOb ^ KTab.G[k]));
    q0[k] = v.x * v.x + v.z * v.z;
    q1[k] = v.y * v.y + v.w * v.w;
    ps.x += q0[k]; ps.y += q1[k];
  }
  const v2 tot = block_reduce_sum2(ps, red);
  const bool k0 = tot.x > 1e-10f, k1 = tot.y > 1e-10f;
  const float t0 = k0 ? 1.0f / tot.x : 0.f, t1 = k1 ? 1.0f / tot.y : 0.f;
  float* o0 = out + r0 * DIM;
  float* o1 = out + (r0 + 1) * DIM;
#pragma unroll
  for (int k = 0; k < 8; ++k) {
    o0[t + k * NT] = k0 ? q0[k] * t0 : (1.0f / DIM);
    o1[t + k * NT] = k1 ? q1[k] * t1 : (1.0f / DIM);
  }
}

extern "C" void kernel_launch(void* const* d_in, const int* in_sizes, int n_in,
                              void* d_out, int out_size, void* d_ws, size_t ws_size,
                              hipStream_t stream) {
  const float* x = (const float*)d_in[0];
  const float* w = (const float*)d_in[1];
  float* out = (float*)d_out;
  const int B = in_sizes[0] / DIM;
  const size_t smem = DIM * 16 + NLAYER * NQ * 4 * sizeof(float2)
                    + (NT / 64) * sizeof(v2);
  qsim_kernel<<<B / 2, NT, smem, stream>>>(x, w, out);
}

// Round 15
// 86.526 us; speedup vs baseline: 1.7058x; 1.7058x over previous
//
#include <hip/hip_runtime.h>
#include <math.h>

#define NQ 12
#define DIM 4096
#define NLAYER 4
#define NT 512

typedef float v2 __attribute__((ext_vector_type(2)));

__device__ __forceinline__ v2 mkv2(float a, float b) { v2 r; r.x = a; r.y = b; return r; }
__device__ __forceinline__ v2 sp(float a) { v2 r; r.x = a; r.y = a; return r; }
__device__ __forceinline__ v2 pkfma(v2 a, float b, v2 c) {
  return __builtin_elementwise_fma(a, sp(b), c);
}

// Compiler reorder fence (zero instructions): keeps LDS ops of consecutive
// wave-private passes in program order; HW executes a wave's DS ops in order
// (premise HW-validated by R14 passing correctness).
#define CFENCE asm volatile("" ::: "memory")

// CNOT-cascade gather map (verified R1-R14): post-perm label y sits at sfun(y).
constexpr int sfun_c(int z) { z ^= z >> 1; z ^= z >> 2; z ^= z >> 4; z ^= z >> 8; return z & (DIM - 1); }
__device__ __forceinline__ int sfun_d(int z) { z ^= z >> 1; z ^= z >> 2; z ^= z >> 4; z ^= z >> 8; return z & (DIM - 1); }
// Swizzle v3 — satisfies the b128 phase criterion (R14 lesson): for EVERY
// pattern below, (lane&7) -> low3 is invertible with lane>>3 fixed, so each
// aligned 8-lane group covers all 8 bank-groups:
//   bit0 ^= z5^z6 ; bit1 ^= z4^z7 ; bit2 ^= z3^z5^z8
// (A=[[001],[010],[101]] inv; B=I inv; E+A*T' inv for the sfun-gather.)
constexpr int swz_c(int z) {
  const int b0 = ((z >> 5) ^ (z >> 6)) & 1;
  const int b1 = ((z >> 4) ^ (z >> 7)) & 1;
  const int b2 = ((z >> 3) ^ (z >> 5) ^ (z >> 8)) & 1;
  return z ^ b0 ^ (b1 << 1) ^ (b2 << 2);
}
__device__ __forceinline__ int swz_d(int z) {
  const int b0 = ((z >> 5) ^ (z >> 6)) & 1;
  const int b1 = ((z >> 4) ^ (z >> 7)) & 1;
  const int b2 = ((z >> 3) ^ (z >> 5) ^ (z >> 8)) & 1;
  return z ^ b0 ^ (b1 << 1) ^ (b2 << 2);
}

// Compile-time XOR byte-offset tables (swz, sfun GF(2)-linear).
struct KT { int A[8], B[8], C[8], D[8], G[8]; };
constexpr KT mkKT() {
  KT k{};
  for (int j = 0; j < 8; ++j) {
    k.A[j] = swz_c(j << 9) << 4;           // alpha: j = z{9-11}
    k.B[j] = swz_c(j << 6) << 4;           // beta:  j = z{6-8}
    k.C[j] = swz_c(j << 3) << 4;           // gamma: j = z{3-5}
    k.D[j] = swz_c(j) << 4;                // delta: j = z{0-2} (also encode)
    k.G[j] = swz_c(sfun_c(j << 9)) << 4;   // CNOT gather composed with alpha
  }
  return k;
}
constexpr KT KTab = mkKT();

__device__ __forceinline__ v2 block_reduce_sum2(v2 v, v2* red) {
  const int tid = threadIdx.x;
#pragma unroll
  for (int off = 32; off > 0; off >>= 1) {
    v.x += __shfl_down(v.x, off, 64);
    v.y += __shfl_down(v.y, off, 64);
  }
  if ((tid & 63) == 0) red[tid >> 6] = v;
  __syncthreads();
  if (tid == 0) {
    v2 s = sp(0.f);
#pragma unroll
    for (int i = 0; i < NT / 64; ++i) s += red[i];
    red[0] = s;
  }
  __syncthreads();
  v2 r = red[0];
  __syncthreads();
  return r;
}

// Packed complex pair update, two rows at once (v_pk_fma_f32 material).
__device__ __forceinline__ void apply_pair(v2& r0, v2& i0, v2& r1, v2& i1,
    const float2 u00, const float2 u01, const float2 u10, const float2 u11) {
  v2 nr0 = pkfma(i1, -u01.y, pkfma(r1, u01.x, pkfma(i0, -u00.y, r0 * sp(u00.x))));
  v2 ni0 = pkfma(r1,  u01.y, pkfma(i1, u01.x, pkfma(r0,  u00.y, i0 * sp(u00.x))));
  v2 nr1 = pkfma(i1, -u11.y, pkfma(r1, u11.x, pkfma(i0, -u10.y, r0 * sp(u10.x))));
  v2 ni1 = pkfma(r1,  u11.y, pkfma(i1, u11.x, pkfma(r0,  u10.y, i0 * sp(u10.x))));
  r0 = nr0; i0 = ni0; r1 = nr1; i1 = ni1;
}

// Pass RT: reg slot-bit i holds z-bit (9-3*RT)+i -> qubit (2+3*RT)-i.
// alpha=RT0, beta=RT1, gamma=RT2, delta=RT3 (R7/R14-verified templates).
template <int RT>
__device__ __forceinline__ void gates3(v2 re[8], v2 im[8], const float2* GL) {
#pragma unroll
  for (int i = 0; i < 3; ++i) {
    const int q = 2 + 3 * RT - i;
    const float2 u00 = GL[q * 4 + 0], u01 = GL[q * 4 + 1];
    const float2 u10 = GL[q * 4 + 2], u11 = GL[q * 4 + 3];
#pragma unroll
    for (int pe = 0; pe < 4; ++pe) {
      const int e0 = ((pe >> i) << (i + 1)) | (pe & ((1 << i) - 1));
      const int e1 = e0 | (1 << i);
      apply_pair(re[e0], im[e0], re[e1], im[e1], u00, u01, u10, u11);
    }
  }
}

#define LOAD8(BB, KARR)                                                \
  _Pragma("unroll")                                                    \
  for (int j = 0; j < 8; ++j) {                                        \
    const float4 v = *(const float4*)(st + ((BB) ^ KTab.KARR[j]));     \
    re[j] = mkv2(v.x, v.y);                                            \
    im[j] = mkv2(v.z, v.w);                                            \
  }
#define STORE8(BB, KARR)                                               \
  _Pragma("unroll")                                                    \
  for (int j = 0; j < 8; ++j)                                          \
    *(float4*)(st + ((BB) ^ KTab.KARR[j])) =                           \
        make_float4(re[j].x, re[j].y, im[j].x, im[j].y);

__global__ __launch_bounds__(NT, 4) void qsim_kernel(
    const float* __restrict__ x, const float* __restrict__ w,
    float* __restrict__ out) {
  extern __shared__ __align__(16) char smem[];
  char*   st   = smem;                           // 64 KB: unit=(re0,re1,im0,im1)
  float2* gmat = (float2*)(smem + DIM * 16);     // 1.5 KB
  v2*     red  = (v2*)(gmat + NLAYER * NQ * 4);  // 64 B

  const int t = threadIdx.x;
  const int lane = t & 63, wave = t >> 6;
  const long r0 = 2L * blockIdx.x;

  // --- gate matrices (48 gates, one thread each) ---
  if (t < NLAYER * NQ) {
    const float* wp = w + t * 3;
    float phi = wp[0], th = wp[1], om = wp[2];
    float sn, cc, sa, ca, sb, cb;
    sincosf(0.5f * th, &sn, &cc);
    sincosf(0.5f * (phi + om), &sa, &ca);
    sincosf(0.5f * (phi - om), &sb, &cb);
    float2* g = &gmat[t * 4];
    g[0] = make_float2(ca * cc, -sa * cc);   // U00
    g[1] = make_float2(-cb * sn, -sb * sn);  // U01
    g[2] = make_float2(cb * sn, -sb * sn);   // U10
    g[3] = make_float2(ca * cc, sa * cc);    // U11
  }

  // --- load 8 consecutive x from each of 2 rows, norms ---
  const float4* xa = (const float4*)(x + r0 * DIM) + t * 2;
  const float4* xb = (const float4*)(x + (r0 + 1) * DIM) + t * 2;
  const float4 a0 = xa[0], a1 = xa[1], b0 = xb[0], b1 = xb[1];
  const float va[8] = {a0.x, a0.y, a0.z, a0.w, a1.x, a1.y, a1.z, a1.w};
  const float vb[8] = {b0.x, b0.y, b0.z, b0.w, b1.x, b1.y, b1.z, b1.w};
  v2 ss = sp(0.f);
#pragma unroll
  for (int e = 0; e < 8; ++e) { ss.x += va[e] * va[e]; ss.y += vb[e] * vb[e]; }
  const v2 nsq = block_reduce_sum2(ss, red);   // barriers also cover gmat init
  const float n0 = sqrtf(nsq.x), n1 = sqrtf(nsq.y);
  const bool ok0 = n0 > 1e-10f, ok1 = n1 > 1e-10f;
  const float i0f = ok0 ? 1.0f / n0 : 0.f, i1f = ok1 ? 1.0f / n1 : 0.f;

  // --- pattern bases (unit index -> byte) ---
  // alpha: z = wave | lane<<3 | j<<9   (ownership class: z{0-2} = wave)
  // beta:  z = wave | (lane&7)<<3 | j<<6 | (lane>>3)<<9   (same class)
  // gamma: z = wave | j<<3 | lane<<6                      (same class)
  // delta: z = j | lane<<3 | wave<<9   (cross-wave; also encode)
  const int baseAb = swz_d(wave | (lane << 3)) << 4;
  const int baseBb = swz_d(wave | ((lane & 7) << 3) | ((lane >> 3) << 9)) << 4;
  const int baseCb = swz_d(wave | (lane << 6)) << 4;
  const int baseDb = swz_d((lane << 3) | (wave << 9)) << 4;
  const int baseGb = swz_d(sfun_d(wave | (lane << 3))) << 4;
  const int baseOb = swz_d(sfun_d(t)) << 4;

  // encode (delta pattern): logical z = t*8 + e
#pragma unroll
  for (int e = 0; e < 8; ++e)
    *(float4*)(st + (baseDb ^ KTab.D[e])) =
        make_float4(ok0 ? va[e] * i0f : 0.015625f,
                    ok1 ? vb[e] * i1f : 0.015625f, 0.f, 0.f);
  __syncthreads();

  v2 re[8], im[8];
#pragma unroll
  for (int L = 0; L < NLAYER; ++L) {
    const float2* GL = &gmat[L * NQ * 4];

    // alpha: z-bits 9-11 (qubits 2,1,0). L>=1 fuses prev layer's CNOT perm.
    if (L == 0) {
      LOAD8(baseAb, A)
      gates3<0>(re, im, GL);
      STORE8(baseAb, A)          // thread-local in-place, no barrier
    } else {
      LOAD8(baseGb, G)
      gates3<0>(re, im, GL);
      __syncthreads();           // all gather reads done before in-place writes
      STORE8(baseAb, A)
    }
    CFENCE;
    // beta: z-bits 6-8 (qubits 5,4,3) — wave-private, NO barrier
    LOAD8(baseBb, B)
    gates3<1>(re, im, GL);
    STORE8(baseBb, B)
    CFENCE;
    // gamma: z-bits 3-5 (qubits 8,7,6) — wave-private, NO barrier
    LOAD8(baseCb, C)
    gates3<2>(re, im, GL);
    STORE8(baseCb, C)
    __syncthreads();             // delta crosses waves
    // delta: z-bits 0-2 (qubits 11,10,9) — thread-local in-place
    LOAD8(baseDb, D)
    gates3<3>(re, im, GL);
    STORE8(baseDb, D)
    __syncthreads();             // next alpha-gather / output reads everything
  }

  // --- output: final perm fused into gather; probs + renormalize, 2 rows ---
  float q0[8], q1[8];
  v2 ps = sp(0.f);
#pragma unroll
  for (int k = 0; k < 8; ++k) {
    const float4 v = *(const float4*)(st + (baseOb ^ KTab.G[k]));
    q0[k] = v.x * v.x + v.z * v.z;
    q1[k] = v.y * v.y + v.w * v.w;
    ps.x += q0[k]; ps.y += q1[k];
  }
  const v2 tot = block_reduce_sum2(ps, red);
  const bool k0 = tot.x > 1e-10f, k1 = tot.y > 1e-10f;
  const float t0 = k0 ? 1.0f / tot.x : 0.f, t1 = k1 ? 1.0f / tot.y : 0.f;
  float* o0 = out + r0 * DIM;
  float* o1 = out + (r0 + 1) * DIM;
#pragma unroll
  for (int k = 0; k < 8; ++k) {
    o0[t + k * NT] = k0 ? q0[k] * t0 : (1.0f / DIM);
    o1[t + k * NT] = k1 ? q1[k] * t1 : (1.0f / DIM);
  }
}

extern "C" void kernel_launch(void* const* d_in, const int* in_sizes, int n_in,
                              void* d_out, int out_size, void* d_ws, size_t ws_size,
                              hipStream_t stream) {
  const float* x = (const float*)d_in[0];
  const float* w = (const float*)d_in[1];
  float* out = (float*)d_out;
  const int B = in_sizes[0] / DIM;
  const size_t smem = DIM * 16 + NLAYER * NQ * 4 * sizeof(float2)
                    + (NT / 64) * sizeof(v2);
  qsim_kernel<<<B / 2, NT, smem, stream>>>(x, w, out);
}

// Round 16
// 82.431 us; speedup vs baseline: 1.7905x; 1.0497x over previous
//
#include <hip/hip_runtime.h>
#include <math.h>

#define NQ 12
#define DIM 4096
#define NLAYER 4
#define NT 512

typedef float v2 __attribute__((ext_vector_type(2)));
typedef float v4f __attribute__((ext_vector_type(4)));

__device__ __forceinline__ v2 sp(float a) { v2 r; r.x = a; r.y = a; return r; }
__device__ __forceinline__ v2 pkfma(v2 a, float b, v2 c) {
  return __builtin_elementwise_fma(a, sp(b), c);
}

// Compiler reorder fence (zero instructions); wave-private pass chain premise
// HW-validated by R14/R15 correctness.
#define CFENCE asm volatile("" ::: "memory")

// CNOT-cascade gather map (verified R1-R15).
constexpr int sfun_c(int z) { z ^= z >> 1; z ^= z >> 2; z ^= z >> 4; z ^= z >> 8; return z & (DIM - 1); }
__device__ __forceinline__ int sfun_d(int z) { z ^= z >> 1; z ^= z >> 2; z ^= z >> 4; z ^= z >> 8; return z & (DIM - 1); }
// Swizzle v3 (HW-validated R15: conflicts 3.2e6): bit0^=z5^z6, bit1^=z4^z7,
// bit2^=z3^z5^z8 — (lane&7)->low3 invertible per 8-lane phase for ALL patterns.
constexpr int swz_c(int z) {
  const int b0 = ((z >> 5) ^ (z >> 6)) & 1;
  const int b1 = ((z >> 4) ^ (z >> 7)) & 1;
  const int b2 = ((z >> 3) ^ (z >> 5) ^ (z >> 8)) & 1;
  return z ^ b0 ^ (b1 << 1) ^ (b2 << 2);
}
__device__ __forceinline__ int swz_d(int z) {
  const int b0 = ((z >> 5) ^ (z >> 6)) & 1;
  const int b1 = ((z >> 4) ^ (z >> 7)) & 1;
  const int b2 = ((z >> 3) ^ (z >> 5) ^ (z >> 8)) & 1;
  return z ^ b0 ^ (b1 << 1) ^ (b2 << 2);
}

// Compile-time XOR byte-offset tables (swz, sfun GF(2)-linear).
struct KT { int A[8], B[8], C[8], D[8], G[8]; };
constexpr KT mkKT() {
  KT k{};
  for (int j = 0; j < 8; ++j) {
    k.A[j] = swz_c(j << 9) << 4;           // alpha: j = z{9-11}
    k.B[j] = swz_c(j << 6) << 4;           // beta:  j = z{6-8}
    k.C[j] = swz_c(j << 3) << 4;           // gamma: j = z{3-5}
    k.D[j] = swz_c(j) << 4;                // delta: j = z{0-2} (also encode)
    k.G[j] = swz_c(sfun_c(j << 9)) << 4;   // CNOT gather composed with alpha
  }
  return k;
}
constexpr KT KTab = mkKT();

__device__ __forceinline__ v2 block_reduce_sum2(v2 v, v2* red) {
  const int tid = threadIdx.x;
#pragma unroll
  for (int off = 32; off > 0; off >>= 1) {
    v.x += __shfl_down(v.x, off, 64);
    v.y += __shfl_down(v.y, off, 64);
  }
  if ((tid & 63) == 0) red[tid >> 6] = v;
  __syncthreads();
  if (tid == 0) {
    v2 s = sp(0.f);
#pragma unroll
    for (int i = 0; i < NT / 64; ++i) s += red[i];
    red[0] = s;
  }
  __syncthreads();
  v2 r = red[0];
  __syncthreads();
  return r;
}

// Packed complex pair update on raw b128 register quads (no repacking).
// A = (re0,re1,im0,im1); g0 = (u00.x,u00.y,u01.x,u01.y); g1 = (u10.*,u11.*).
__device__ __forceinline__ void apply_pair(v4f& A, v4f& B, const v4f g0, const v4f g1) {
  const v2 ar = A.lo, ai = A.hi, br = B.lo, bi = B.hi;
  const v2 nr0 = pkfma(bi, -g0.w, pkfma(br, g0.z, pkfma(ai, -g0.y, ar * sp(g0.x))));
  const v2 ni0 = pkfma(br,  g0.w, pkfma(bi, g0.z, pkfma(ar,  g0.y, ai * sp(g0.x))));
  const v2 nr1 = pkfma(bi, -g1.w, pkfma(br, g1.z, pkfma(ai, -g1.y, ar * sp(g1.x))));
  const v2 ni1 = pkfma(br,  g1.w, pkfma(bi, g1.z, pkfma(ar,  g1.y, ai * sp(g1.x))));
  A.lo = nr0; A.hi = ni0; B.lo = nr1; B.hi = ni1;
}

// Pass RT: reg slot-bit i holds z-bit (9-3*RT)+i -> qubit (2+3*RT)-i.
template <int RT>
__device__ __forceinline__ void gates3(v4f s[8], const float2* GL) {
#pragma unroll
  for (int i = 0; i < 3; ++i) {
    const int q = 2 + 3 * RT - i;
    const v4f g0 = *(const v4f*)&GL[q * 4];      // one b128: U00,U01
    const v4f g1 = *(const v4f*)&GL[q * 4 + 2];  // one b128: U10,U11
#pragma unroll
    for (int pe = 0; pe < 4; ++pe) {
      const int e0 = ((pe >> i) << (i + 1)) | (pe & ((1 << i) - 1));
      apply_pair(s[e0], s[e0 | (1 << i)], g0, g1);
    }
  }
}

#define LOAD8(ADDR)                                       \
  _Pragma("unroll")                                       \
  for (int j = 0; j < 8; ++j)                             \
    s[j] = *(const v4f*)(st + ADDR[j]);
#define STORE8(ADDR)                                      \
  _Pragma("unroll")                                       \
  for (int j = 0; j < 8; ++j)                             \
    *(v4f*)(st + ADDR[j]) = s[j];

__global__ __launch_bounds__(NT, 4) void qsim_kernel(
    const float* __restrict__ x, const float* __restrict__ w,
    float* __restrict__ out) {
  extern __shared__ __align__(16) char smem[];
  char*   st   = smem;                           // 64 KB: unit=(re0,re1,im0,im1)
  float2* gmat = (float2*)(smem + DIM * 16);     // 1.5 KB
  v2*     red  = (v2*)(gmat + NLAYER * NQ * 4);  // 64 B

  const int t = threadIdx.x;
  const int lane = t & 63, wave = t >> 6;
  const long r0 = 2L * blockIdx.x;

  // --- gate matrices (48 gates, one thread each) ---
  if (t < NLAYER * NQ) {
    const float* wp = w + t * 3;
    float phi = wp[0], th = wp[1], om = wp[2];
    float sn, cc, sa, ca, sb, cb;
    sincosf(0.5f * th, &sn, &cc);
    sincosf(0.5f * (phi + om), &sa, &ca);
    sincosf(0.5f * (phi - om), &sb, &cb);
    float2* g = &gmat[t * 4];
    g[0] = make_float2(ca * cc, -sa * cc);   // U00
    g[1] = make_float2(-cb * sn, -sb * sn);  // U01
    g[2] = make_float2(cb * sn, -sb * sn);   // U10
    g[3] = make_float2(ca * cc, sa * cc);    // U11
  }

  // --- load 8 consecutive x from each of 2 rows, norms ---
  const float4* xa = (const float4*)(x + r0 * DIM) + t * 2;
  const float4* xb = (const float4*)(x + (r0 + 1) * DIM) + t * 2;
  const float4 a0 = xa[0], a1 = xa[1], b0 = xb[0], b1 = xb[1];
  const float va[8] = {a0.x, a0.y, a0.z, a0.w, a1.x, a1.y, a1.z, a1.w};
  const float vb[8] = {b0.x, b0.y, b0.z, b0.w, b1.x, b1.y, b1.z, b1.w};
  v2 ss = sp(0.f);
#pragma unroll
  for (int e = 0; e < 8; ++e) { ss.x += va[e] * va[e]; ss.y += vb[e] * vb[e]; }
  const v2 nsq = block_reduce_sum2(ss, red);   // barriers also cover gmat init
  const float n0 = sqrtf(nsq.x), n1 = sqrtf(nsq.y);
  const bool ok0 = n0 > 1e-10f, ok1 = n1 > 1e-10f;
  const float i0f = ok0 ? 1.0f / n0 : 0.f, i1f = ok1 ? 1.0f / n1 : 0.f;

  // --- precomputed byte addresses per pattern (loop-invariant, registers) ---
  // alpha: z = wave | lane<<3 | j<<9 ; beta: z = wave|(lane&7)<<3|j<<6|(lane>>3)<<9
  // gamma: z = wave | j<<3 | lane<<6 ; delta: z = j | lane<<3 | wave<<9
  const int baseAb = swz_d(wave | (lane << 3)) << 4;
  const int baseBb = swz_d(wave | ((lane & 7) << 3) | ((lane >> 3) << 9)) << 4;
  const int baseCb = swz_d(wave | (lane << 6)) << 4;
  const int baseDb = swz_d((lane << 3) | (wave << 9)) << 4;
  const int baseGb = swz_d(sfun_d(wave | (lane << 3))) << 4;
  const int baseOb = swz_d(sfun_d(t)) << 4;
  int aA[8], aB[8], aC[8], aD[8], aG[8];
#pragma unroll
  for (int j = 0; j < 8; ++j) {
    aA[j] = baseAb ^ KTab.A[j];
    aB[j] = baseBb ^ KTab.B[j];
    aC[j] = baseCb ^ KTab.C[j];
    aD[j] = baseDb ^ KTab.D[j];
    aG[j] = baseGb ^ KTab.G[j];
  }

  // encode (delta pattern): logical z = t*8 + e
#pragma unroll
  for (int e = 0; e < 8; ++e) {
    v4f u;
    u.x = ok0 ? va[e] * i0f : 0.015625f;
    u.y = ok1 ? vb[e] * i1f : 0.015625f;
    u.z = 0.f; u.w = 0.f;
    *(v4f*)(st + aD[e]) = u;
  }
  __syncthreads();

  v4f s[8];
#pragma unroll
  for (int L = 0; L < NLAYER; ++L) {
    const float2* GL = &gmat[L * NQ * 4];

    // alpha: z-bits 9-11 (qubits 2,1,0). L>=1 fuses prev layer's CNOT perm.
    if (L == 0) {
      LOAD8(aA)
      gates3<0>(s, GL);
      STORE8(aA)                 // thread-local in-place, no barrier
    } else {
      LOAD8(aG)
      gates3<0>(s, GL);
      __syncthreads();           // all gather reads done before in-place writes
      STORE8(aA)
    }
    CFENCE;
    // beta: z-bits 6-8 (qubits 5,4,3) — wave-private, NO barrier
    LOAD8(aB)
    gates3<1>(s, GL);
    STORE8(aB)
    CFENCE;
    // gamma: z-bits 3-5 (qubits 8,7,6) — wave-private, NO barrier
    LOAD8(aC)
    gates3<2>(s, GL);
    STORE8(aC)
    __syncthreads();             // delta crosses waves
    // delta: z-bits 0-2 (qubits 11,10,9) — thread-local in-place
    LOAD8(aD)
    gates3<3>(s, GL);
    STORE8(aD)
    __syncthreads();             // next alpha-gather / output reads everything
  }

  // --- output: final perm fused into gather; probs + renormalize, 2 rows ---
  float q0[8], q1[8];
  v2 ps = sp(0.f);
#pragma unroll
  for (int k = 0; k < 8; ++k) {
    const v4f v = *(const v4f*)(st + ((baseOb ^ KTab.G[k])));
    q0[k] = v.x * v.x + v.z * v.z;
    q1[k] = v.y * v.y + v.w * v.w;
    ps.x += q0[k]; ps.y += q1[k];
  }
  const v2 tot = block_reduce_sum2(ps, red);
  const bool k0 = tot.x > 1e-10f, k1 = tot.y > 1e-10f;
  const float t0 = k0 ? 1.0f / tot.x : 0.f, t1 = k1 ? 1.0f / tot.y : 0.f;
  float* o0 = out + r0 * DIM;
  float* o1 = out + (r0 + 1) * DIM;
#pragma unroll
  for (int k = 0; k < 8; ++k) {
    o0[t + k * NT] = k0 ? q0[k] * t0 : (1.0f / DIM);
    o1[t + k * NT] = k1 ? q1[k] * t1 : (1.0f / DIM);
  }
}

extern "C" void kernel_launch(void* const* d_in, const int* in_sizes, int n_in,
                              void* d_out, int out_size, void* d_ws, size_t ws_size,
                              hipStream_t stream) {
  const float* x = (const float*)d_in[0];
  const float* w = (const float*)d_in[1];
  float* out = (float*)d_out;
  const int B = in_sizes[0] / DIM;
  const size_t smem = DIM * 16 + NLAYER * NQ * 4 * sizeof(float2)
                    + (NT / 64) * sizeof(v2);
  qsim_kernel<<<B / 2, NT, smem, stream>>>(x, w, out);
}

// Round 17
// 78.228 us; speedup vs baseline: 1.8867x; 1.0537x over previous
//
#include <hip/hip_runtime.h>
#include <math.h>

#define NQ 12
#define DIM 4096
#define NLAYER 4
#define NT 512

typedef float v2 __attribute__((ext_vector_type(2)));
typedef float v4f __attribute__((ext_vector_type(4)));

__device__ __forceinline__ v2 sp(float a) { v2 r; r.x = a; r.y = a; return r; }
__device__ __forceinline__ v2 pkfma(v2 a, float b, v2 c) {
  return __builtin_elementwise_fma(a, sp(b), c);
}

// Compiler reorder fence (zero instructions); wave-private pass chain premise
// HW-validated by R14/R15/R16 correctness.
#define CFENCE asm volatile("" ::: "memory")

// CNOT-cascade gather map (verified R1-R16).
constexpr int sfun_c(int z) { z ^= z >> 1; z ^= z >> 2; z ^= z >> 4; z ^= z >> 8; return z & (DIM - 1); }
__device__ __forceinline__ int sfun_d(int z) { z ^= z >> 1; z ^= z >> 2; z ^= z >> 4; z ^= z >> 8; return z & (DIM - 1); }
// Swizzle v3 (HW-validated R15/R16: conflicts 3.2e6): bit0^=z5^z6,
// bit1^=z4^z7, bit2^=z3^z5^z8.
constexpr int swz_c(int z) {
  const int b0 = ((z >> 5) ^ (z >> 6)) & 1;
  const int b1 = ((z >> 4) ^ (z >> 7)) & 1;
  const int b2 = ((z >> 3) ^ (z >> 5) ^ (z >> 8)) & 1;
  return z ^ b0 ^ (b1 << 1) ^ (b2 << 2);
}
__device__ __forceinline__ int swz_d(int z) {
  const int b0 = ((z >> 5) ^ (z >> 6)) & 1;
  const int b1 = ((z >> 4) ^ (z >> 7)) & 1;
  const int b2 = ((z >> 3) ^ (z >> 5) ^ (z >> 8)) & 1;
  return z ^ b0 ^ (b1 << 1) ^ (b2 << 2);
}

// Compile-time XOR byte-offset tables (swz, sfun GF(2)-linear).
struct KT { int A[8], B[8], C[8], D[8], G[8]; };
constexpr KT mkKT() {
  KT k{};
  for (int j = 0; j < 8; ++j) {
    k.A[j] = swz_c(j << 9) << 4;           // alpha: j = z{9-11}
    k.B[j] = swz_c(j << 6) << 4;           // beta:  j = z{6-8}
    k.C[j] = swz_c(j << 3) << 4;           // gamma: j = z{3-5}
    k.D[j] = swz_c(j) << 4;                // delta: j = z{0-2} (also encode)
    k.G[j] = swz_c(sfun_c(j << 9)) << 4;   // CNOT gather composed with alpha
  }
  return k;
}
constexpr KT KTab = mkKT();

__device__ __forceinline__ v2 block_reduce_sum2(v2 v, v2* red) {
  const int tid = threadIdx.x;
#pragma unroll
  for (int off = 32; off > 0; off >>= 1) {
    v.x += __shfl_down(v.x, off, 64);
    v.y += __shfl_down(v.y, off, 64);
  }
  if ((tid & 63) == 0) red[tid >> 6] = v;
  __syncthreads();
  if (tid == 0) {
    v2 s = sp(0.f);
#pragma unroll
    for (int i = 0; i < NT / 64; ++i) s += red[i];
    red[0] = s;
  }
  __syncthreads();
  v2 r = red[0];
  __syncthreads();
  return r;
}

// Packed complex pair update on raw b128 register quads.
// A = (re0,re1,im0,im1); g0 = (u00.x,u00.y,u01.x,u01.y); g1 = (u10.*,u11.*).
__device__ __forceinline__ void apply_pair(v4f& A, v4f& B, const v4f g0, const v4f g1) {
  const v2 ar = A.lo, ai = A.hi, br = B.lo, bi = B.hi;
  const v2 nr0 = pkfma(bi, -g0.w, pkfma(br, g0.z, pkfma(ai, -g0.y, ar * sp(g0.x))));
  const v2 ni0 = pkfma(br,  g0.w, pkfma(bi, g0.z, pkfma(ar,  g0.y, ai * sp(g0.x))));
  const v2 nr1 = pkfma(bi, -g1.w, pkfma(br, g1.z, pkfma(ai, -g1.y, ar * sp(g1.x))));
  const v2 ni1 = pkfma(br,  g1.w, pkfma(bi, g1.z, pkfma(ar,  g1.y, ai * sp(g1.x))));
  A.lo = nr0; A.hi = ni0; B.lo = nr1; B.hi = ni1;
}

// Pass RT: reg slot-bit i holds z-bit (9-3*RT)+i -> qubit (2+3*RT)-i.
// GW = layer base in the precomputed global gate table (uniform address,
// compile-time offsets -> scalar s_load into SGPRs).
template <int RT>
__device__ __forceinline__ void gates3(v4f s[8], const float* __restrict__ GW) {
#pragma unroll
  for (int i = 0; i < 3; ++i) {
    const int q = 2 + 3 * RT - i;
    const v4f g0 = *(const v4f*)(GW + q * 8);
    const v4f g1 = *(const v4f*)(GW + q * 8 + 4);
#pragma unroll
    for (int pe = 0; pe < 4; ++pe) {
      const int e0 = ((pe >> i) << (i + 1)) | (pe & ((1 << i) - 1));
      apply_pair(s[e0], s[e0 | (1 << i)], g0, g1);
    }
  }
}

#define LOAD8(ADDR)                                       \
  _Pragma("unroll")                                       \
  for (int j = 0; j < 8; ++j)                             \
    s[j] = *(const v4f*)(st + ADDR[j]);
#define STORE8(ADDR)                                      \
  _Pragma("unroll")                                       \
  for (int j = 0; j < 8; ++j)                             \
    *(v4f*)(st + ADDR[j]) = s[j];

// --- prep: 48 gate matrices -> gw[48*8] in global (once per launch) ---
__global__ void prep_gates(const float* __restrict__ w, float* __restrict__ gw) {
  const int t = threadIdx.x;
  if (t < NLAYER * NQ) {
    const float* wp = w + t * 3;
    float phi = wp[0], th = wp[1], om = wp[2];
    float sn, cc, sa, ca, sb, cb;
    sincosf(0.5f * th, &sn, &cc);
    sincosf(0.5f * (phi + om), &sa, &ca);
    sincosf(0.5f * (phi - om), &sb, &cb);
    float* g = gw + t * 8;
    g[0] = ca * cc;  g[1] = -sa * cc;   // U00
    g[2] = -cb * sn; g[3] = -sb * sn;   // U01
    g[4] = cb * sn;  g[5] = -sb * sn;   // U10
    g[6] = ca * cc;  g[7] = sa * cc;    // U11
  }
}

__global__ __launch_bounds__(NT, 4) void qsim_kernel(
    const float* __restrict__ x, const float* __restrict__ gw,
    float* __restrict__ out) {
  extern __shared__ __align__(16) char smem[];
  char* st  = smem;                      // 64 KB: unit=(re0,re1,im0,im1)
  v2*   red = (v2*)(smem + DIM * 16);    // 64 B

  const int t = threadIdx.x;
  const int lane = t & 63, wave = t >> 6;
  const long r0 = 2L * blockIdx.x;

  // --- load 8 consecutive x from each of 2 rows, norms ---
  const float4* xa = (const float4*)(x + r0 * DIM) + t * 2;
  const float4* xb = (const float4*)(x + (r0 + 1) * DIM) + t * 2;
  const float4 a0 = xa[0], a1 = xa[1], b0 = xb[0], b1 = xb[1];
  const float va[8] = {a0.x, a0.y, a0.z, a0.w, a1.x, a1.y, a1.z, a1.w};
  const float vb[8] = {b0.x, b0.y, b0.z, b0.w, b1.x, b1.y, b1.z, b1.w};
  v2 ss = sp(0.f);
#pragma unroll
  for (int e = 0; e < 8; ++e) { ss.x += va[e] * va[e]; ss.y += vb[e] * vb[e]; }
  const v2 nsq = block_reduce_sum2(ss, red);
  const float n0 = sqrtf(nsq.x), n1 = sqrtf(nsq.y);
  const bool ok0 = n0 > 1e-10f, ok1 = n1 > 1e-10f;
  const float i0f = ok0 ? 1.0f / n0 : 0.f, i1f = ok1 ? 1.0f / n1 : 0.f;

  // --- precomputed byte addresses per pattern (loop-invariant, registers) ---
  const int baseAb = swz_d(wave | (lane << 3)) << 4;
  const int baseBb = swz_d(wave | ((lane & 7) << 3) | ((lane >> 3) << 9)) << 4;
  const int baseCb = swz_d(wave | (lane << 6)) << 4;
  const int baseDb = swz_d((lane << 3) | (wave << 9)) << 4;
  const int baseGb = swz_d(sfun_d(wave | (lane << 3))) << 4;
  const int baseOb = swz_d(sfun_d(t)) << 4;
  int aA[8], aB[8], aC[8], aD[8], aG[8];
#pragma unroll
  for (int j = 0; j < 8; ++j) {
    aA[j] = baseAb ^ KTab.A[j];
    aB[j] = baseBb ^ KTab.B[j];
    aC[j] = baseCb ^ KTab.C[j];
    aD[j] = baseDb ^ KTab.D[j];
    aG[j] = baseGb ^ KTab.G[j];
  }

  // encode (delta pattern): logical z = t*8 + e
#pragma unroll
  for (int e = 0; e < 8; ++e) {
    v4f u;
    u.x = ok0 ? va[e] * i0f : 0.015625f;
    u.y = ok1 ? vb[e] * i1f : 0.015625f;
    u.z = 0.f; u.w = 0.f;
    *(v4f*)(st + aD[e]) = u;
  }
  __syncthreads();

  v4f s[8];
#pragma unroll
  for (int L = 0; L < NLAYER; ++L) {
    const float* GW = gw + L * (NQ * 8);

    // alpha: z-bits 9-11 (qubits 2,1,0). L>=1 fuses prev layer's CNOT perm.
    if (L == 0) {
      LOAD8(aA)
      gates3<0>(s, GW);
      STORE8(aA)                 // thread-local in-place, no barrier
    } else {
      LOAD8(aG)
      gates3<0>(s, GW);
      __syncthreads();           // all gather reads done before in-place writes
      STORE8(aA)
    }
    CFENCE;
    // beta: z-bits 6-8 (qubits 5,4,3) — wave-private, NO barrier
    LOAD8(aB)
    gates3<1>(s, GW);
    STORE8(aB)
    CFENCE;
    // gamma: z-bits 3-5 (qubits 8,7,6) — wave-private, NO barrier
    LOAD8(aC)
    gates3<2>(s, GW);
    STORE8(aC)
    __syncthreads();             // delta crosses waves
    // delta: z-bits 0-2 (qubits 11,10,9) — thread-local in-place
    LOAD8(aD)
    gates3<3>(s, GW);
    STORE8(aD)
    __syncthreads();             // next alpha-gather / output reads everything
  }

  // --- output: final perm fused into gather; probs + renormalize, 2 rows ---
  float q0[8], q1[8];
  v2 ps = sp(0.f);
#pragma unroll
  for (int k = 0; k < 8; ++k) {
    const v4f v = *(const v4f*)(st + (baseOb ^ KTab.G[k]));
    q0[k] = v.x * v.x + v.z * v.z;
    q1[k] = v.y * v.y + v.w * v.w;
    ps.x += q0[k]; ps.y += q1[k];
  }
  const v2 tot = block_reduce_sum2(ps, red);
  const bool k0 = tot.x > 1e-10f, k1 = tot.y > 1e-10f;
  const float t0 = k0 ? 1.0f / tot.x : 0.f, t1 = k1 ? 1.0f / tot.y : 0.f;
  float* o0 = out + r0 * DIM;
  float* o1 = out + (r0 + 1) * DIM;
#pragma unroll
  for (int k = 0; k < 8; ++k) {
    o0[t + k * NT] = k0 ? q0[k] * t0 : (1.0f / DIM);
    o1[t + k * NT] = k1 ? q1[k] * t1 : (1.0f / DIM);
  }
}

extern "C" void kernel_launch(void* const* d_in, const int* in_sizes, int n_in,
                              void* d_out, int out_size, void* d_ws, size_t ws_size,
                              hipStream_t stream) {
  const float* x = (const float*)d_in[0];
  const float* w = (const float*)d_in[1];
  float* out = (float*)d_out;
  float* gw = (float*)d_ws;  // 48 gates x 8 floats = 1536 B
  const int B = in_sizes[0] / DIM;
  prep_gates<<<1, 64, 0, stream>>>(w, gw);
  const size_t smem = DIM * 16 + (NT / 64) * sizeof(v2);
  qsim_kernel<<<B / 2, NT, smem, stream>>>(x, gw, out);
}